// Round 12
// baseline (42.827 us; speedup 1.0000x reference)
//
#include <hip/hip_runtime.h>
#include <cmath>

#define EPSN 1e-12f

typedef _Float16 half8 __attribute__((ext_vector_type(8)));
typedef float f32x4 __attribute__((ext_vector_type(4)));

// ---------------------------------------------------------------------------
// scores_kernel: one block per bn, 512 threads = 8 waves (two r10 half-blocks
// glued in parallel). Per-thread hot path is r10-EXACT (same loads, CVT hi/lo,
// B-image layout, 3-term MFMA, epilogue). Shared: q-prologue, 256-token mask
// compaction, barrier train (10/bn vs 20/bn), Aimg. Thread (s=t&255, kh=t>>8)
// owns 64B of compacted token slot s per K-chunk. 4 chunks, depth-2 register
// prefetch, lgkmcnt-only barriers. Pad slots: no loads, zeroed B-columns
// (chunk 0), invS=0 -> inject sim=0 into max iff masked tokens exist
// (reference-exact). Writes scores[bn] directly.
// ---------------------------------------------------------------------------
__global__ __launch_bounds__(512, 4) void scores_kernel(
    const float* __restrict__ qr, const float* __restrict__ doc,
    const int* __restrict__ mask, float* __restrict__ scores) {
    __shared__ __align__(16) char Aimg[16384];   // [qt2][kstep4][hl2][1024B]
    __shared__ __align__(16) char Bimg[32768];   // [tile16][hl2][quad4*16+col][16B]
    __shared__ float ssPart[512];
    __shared__ float invS[256];
    __shared__ int   compactS[256];
    __shared__ int   cntW[4];
    __shared__ float wq[8][32];

    int t = threadIdx.x, g = blockIdx.x;         // g == bn
    int b = g >> 4;
    int w = t >> 6, lane = t & 63, col = lane & 15;

    // ---- q loads first (waves 0-3; arrive during compaction) ----
    int row = (t & 255) >> 3, jb = t & 7;
    float4 v0, v1, v2, v3;
    if (t < 256) {
        const float4* qsrc = (const float4*)(qr + ((size_t)b * 32 + row) * 128 + jb * 16);
        v0 = qsrc[0]; v1 = qsrc[1]; v2 = qsrc[2]; v3 = qsrc[3];
    }

    // ---- mask + ballot compaction over 256 tokens (waves 0-3) ----
    int myMask = 0;
    unsigned long long bal = 0;
    if (t < 256) {
        myMask = mask[g * 256 + t];
        bal = __ballot(myMask != 0);
        if (lane == 0) cntW[w] = __popcll(bal);
    }
    __syncthreads();                              // barrier 1
    int cnt = cntW[0] + cntW[1] + cntW[2] + cntW[3];
    if (myMask) {                                 // only t<256 possible
        int prefix = __popcll(bal & ((1ull << lane) - 1));
        int basec = 0;
        if (w >= 1) basec += cntW[0];
        if (w >= 2) basec += cntW[1];
        if (w >= 3) basec += cntW[2];
        compactS[basec + prefix] = t;
    }
    __syncthreads();

    int s = t & 255, kh = t >> 8;
    bool real = (s < cnt);
    int tokc = real ? compactS[s] : 0;

    // ---- doc prefetch: chunks 0 and 1 (guarded; exec-masked if pad) ----
    const float4* dsrc = (const float4*)(doc + ((size_t)g * 256 + tokc) * 128) + kh * 4;
    float4 rA0, rA1, rA2, rA3, rB0, rB1, rB2, rB3, rC0, rC1, rC2, rC3;
    if (real) {
        rA0 = dsrc[0];  rA1 = dsrc[1];  rA2 = dsrc[2];  rA3 = dsrc[3];
        rB0 = dsrc[8];  rB1 = dsrc[9];  rB2 = dsrc[10]; rB3 = dsrc[11];
    }

    // ---- q prologue: normalize + f16 hi/lo split + A-image (r10-exact) ----
    if (t < 256) {
        float ss = v0.x*v0.x + v0.y*v0.y + v0.z*v0.z + v0.w*v0.w
                 + v1.x*v1.x + v1.y*v1.y + v1.z*v1.z + v1.w*v1.w
                 + v2.x*v2.x + v2.y*v2.y + v2.z*v2.z + v2.w*v2.w
                 + v3.x*v3.x + v3.y*v3.y + v3.z*v3.z + v3.w*v3.w;
        ss += __shfl_xor(ss, 1); ss += __shfl_xor(ss, 2); ss += __shfl_xor(ss, 4);
        float inv = 1.0f / fmaxf(sqrtf(ss), EPSN);
        int qt = row >> 4, kstep = jb >> 1;
        float4 vv[4] = { v0, v1, v2, v3 };
#pragma unroll
        for (int khh = 0; khh < 2; ++khh) {
            float xs[8] = { vv[2*khh].x,   vv[2*khh].y,   vv[2*khh].z,   vv[2*khh].w,
                            vv[2*khh+1].x, vv[2*khh+1].y, vv[2*khh+1].z, vv[2*khh+1].w };
            half8 hh, hl;
#pragma unroll
            for (int e = 0; e < 8; ++e) {
                float x = xs[e] * inv;
                _Float16 hv = (_Float16)x;
                hh[e] = hv;
                hl[e] = (_Float16)(x - (float)hv);
            }
            int quad = (jb & 1) * 2 + khh;
            int base = ((qt * 4 + kstep) * 2) * 1024 + ((row & 15) + quad * 16) * 16;
            *(half8*)(Aimg + base)        = hh;
            *(half8*)(Aimg + base + 1024) = hl;
        }
    }
    asm volatile("s_waitcnt lgkmcnt(0)" ::: "memory");
    __builtin_amdgcn_s_barrier();

    f32x4 acc[2][2];
    f32x4 zero = {0.f, 0.f, 0.f, 0.f};
    acc[0][0] = zero; acc[0][1] = zero; acc[1][0] = zero; acc[1][1] = zero;
    float ss_d = 0.f;

    int bo_base = (s >> 4) * 2048 + (2 * kh) * 256 + (s & 15) * 16;

#define CHUNK(C, P0, P1, P2, P3, N0, N1, N2, N3, PREF, ISLAST) do {           \
    if ((PREF) && real) {                                                     \
        N0 = dsrc[(C + 2) * 8 + 0]; N1 = dsrc[(C + 2) * 8 + 1];               \
        N2 = dsrc[(C + 2) * 8 + 2]; N3 = dsrc[(C + 2) * 8 + 3];               \
    }                                                                         \
    if (real) {                                                               \
        ss_d += P0.x*P0.x + P0.y*P0.y + P0.z*P0.z + P0.w*P0.w;                \
        ss_d += P1.x*P1.x + P1.y*P1.y + P1.z*P1.z + P1.w*P1.w;                \
        ss_d += P2.x*P2.x + P2.y*P2.y + P2.z*P2.z + P2.w*P2.w;                \
        ss_d += P3.x*P3.x + P3.y*P3.y + P3.z*P3.z + P3.w*P3.w;                \
        float xa[8] = { P0.x, P0.y, P0.z, P0.w, P1.x, P1.y, P1.z, P1.w };     \
        float xb[8] = { P2.x, P2.y, P2.z, P2.w, P3.x, P3.y, P3.z, P3.w };     \
        half8 hha, hla, hhb, hlb;                                             \
        _Pragma("unroll")                                                     \
        for (int e = 0; e < 8; ++e) {                                         \
            float x = xa[e]; _Float16 hv = (_Float16)x;                       \
            hha[e] = hv; hla[e] = (_Float16)(x - (float)hv);                  \
            float y = xb[e]; _Float16 hw = (_Float16)y;                       \
            hhb[e] = hw; hlb[e] = (_Float16)(y - (float)hw);                  \
        }                                                                     \
        *(half8*)(Bimg + bo_base)              = hha;                         \
        *(half8*)(Bimg + bo_base + 1024)       = hla;                         \
        *(half8*)(Bimg + bo_base + 256)        = hhb;                         \
        *(half8*)(Bimg + bo_base + 256 + 1024) = hlb;                         \
    } else if ((C) == 0) {                                                    \
        half8 hz = {0,0,0,0,0,0,0,0};                                         \
        *(half8*)(Bimg + bo_base)              = hz;                          \
        *(half8*)(Bimg + bo_base + 1024)       = hz;                          \
        *(half8*)(Bimg + bo_base + 256)        = hz;                          \
        *(half8*)(Bimg + bo_base + 256 + 1024) = hz;                          \
    }                                                                         \
    if (ISLAST) ssPart[t] = ss_d;                                             \
    asm volatile("s_waitcnt lgkmcnt(0)" ::: "memory");                        \
    __builtin_amdgcn_s_barrier();                                             \
    if ((ISLAST) && t < 256) {                                                \
        float sst = ssPart[t] + ssPart[t + 256];                              \
        invS[t] = (t < cnt) ? (1.0f / fmaxf(sqrtf(sst), EPSN)) : 0.0f;        \
    }                                                                         \
    {                                                                         \
        int lo = lane << 4;                                                   \
        half8 a0h = *(const half8*)(Aimg + (((C) * 2 + 0) << 10) + lo);       \
        half8 a0l = *(const half8*)(Aimg + (((C) * 2 + 1) << 10) + lo);       \
        half8 a1h = *(const half8*)(Aimg + (((4 + (C)) * 2 + 0) << 10) + lo); \
        half8 a1l = *(const half8*)(Aimg + (((4 + (C)) * 2 + 1) << 10) + lo); \
        _Pragma("unroll")                                                     \
        for (int nt = 0; nt < 2; ++nt) {                                      \
            int tile = w * 2 + nt;                                            \
            half8 bh = *(const half8*)(Bimg + tile * 2048 + lo);              \
            half8 bl = *(const half8*)(Bimg + tile * 2048 + 1024 + lo);       \
            acc[0][nt] = __builtin_amdgcn_mfma_f32_16x16x32_f16(a0l, bh, acc[0][nt], 0, 0, 0); \
            acc[0][nt] = __builtin_amdgcn_mfma_f32_16x16x32_f16(a0h, bl, acc[0][nt], 0, 0, 0); \
            acc[0][nt] = __builtin_amdgcn_mfma_f32_16x16x32_f16(a0h, bh, acc[0][nt], 0, 0, 0); \
            acc[1][nt] = __builtin_amdgcn_mfma_f32_16x16x32_f16(a1l, bh, acc[1][nt], 0, 0, 0); \
            acc[1][nt] = __builtin_amdgcn_mfma_f32_16x16x32_f16(a1h, bl, acc[1][nt], 0, 0, 0); \
            acc[1][nt] = __builtin_amdgcn_mfma_f32_16x16x32_f16(a1h, bh, acc[1][nt], 0, 0, 0); \
        }                                                                     \
    }                                                                         \
    asm volatile("s_waitcnt lgkmcnt(0)" ::: "memory");                        \
    __builtin_amdgcn_s_barrier();                                             \
} while (0)

    // rotation: c0=A c1=B c2=C c3=A; prefetch c+2 during chunk c
    CHUNK(0, rA0, rA1, rA2, rA3, rC0, rC1, rC2, rC3, 1, false);
    CHUNK(1, rB0, rB1, rB2, rB3, rA0, rA1, rA2, rA3, 1, false);
    CHUNK(2, rC0, rC1, rC2, rC3, rB0, rB1, rB2, rB3, 0, false);
    CHUNK(3, rA0, rA1, rA2, rA3, rB0, rB1, rB2, rB3, 0, true);
#undef CHUNK

    // ---- epilogue: inv-norm, max over wave's 32 token slots (r10-exact) ----
    float inv0 = invS[w * 32 + col];
    float inv1 = invS[w * 32 + 16 + col];
    float m8[8];
#pragma unroll
    for (int qt = 0; qt < 2; ++qt)
#pragma unroll
        for (int rr = 0; rr < 4; ++rr)
            m8[qt * 4 + rr] = fmaxf(acc[qt][0][rr] * inv0, acc[qt][1][rr] * inv1);
#pragma unroll
    for (int off = 1; off < 16; off <<= 1)
#pragma unroll
        for (int i = 0; i < 8; ++i) m8[i] = fmaxf(m8[i], __shfl_xor(m8[i], off));
    if (col == 0) {
        int rg = lane >> 4;   // C/D: row = (lane>>4)*4 + reg (m89-verified)
#pragma unroll
        for (int qt = 0; qt < 2; ++qt)
#pragma unroll
            for (int rr = 0; rr < 4; ++rr) wq[w][qt * 16 + rg * 4 + rr] = m8[qt * 4 + rr];
    }
    __syncthreads();
    if (w == 0) {
        float v = 0.f;
        if (lane < 32) {
            v = wq[0][lane];
#pragma unroll
            for (int ww = 1; ww < 8; ++ww) v = fmaxf(v, wq[ww][lane]);
        }
#pragma unroll
        for (int off = 1; off < 64; off <<= 1) v += __shfl_xor(v, off);
        if (lane == 0) scores[g] = v;
    }
}

// ---------------------------------------------------------------------------
// loss_kernel: single block, 1024 threads (r6-validated). Reads scores
// directly; 16384 pairs -> scalar.
// ---------------------------------------------------------------------------
__global__ __launch_bounds__(1024) void loss_kernel(const float* __restrict__ scores,
                                                    const float* __restrict__ labels,
                                                    float* __restrict__ out) {
    __shared__ float scL[1024];
    __shared__ float labL[2048];
    __shared__ float wsum[16];
    int t = threadIdx.x;
    labL[t] = labels[t];
    labL[t + 1024] = labels[t + 1024];
    scL[t] = scores[t];
    __syncthreads();
    float total = 0.f;
#pragma unroll
    for (int it = 0; it < 16; ++it) {
        int p = t + it * 1024;
        int b = p >> 8, ij = p & 255, i = ij >> 4, j = ij & 15;
        float ysi = labL[b * 32 + i], ysj = labL[b * 32 + j];
        if (ysi - ysj > 0.f) {
            float wgt = fabsf(labL[b * 32 + 16 + i] - labL[b * 32 + 16 + j]);
            float d = (i <= j) ? (scL[b * 16 + i] - scL[b * 16 + j]) : 0.f;
            total += log1pf(expf(-d)) * wgt;
        }
    }
#pragma unroll
    for (int off = 1; off < 64; off <<= 1) total += __shfl_xor(total, off);
    int lane = t & 63;
    if (lane == 0) wsum[t >> 6] = total;
    __syncthreads();
    if (t < 64) {
        float v = (t < 16) ? wsum[t] : 0.f;
#pragma unroll
        for (int off = 1; off < 64; off <<= 1) v += __shfl_xor(v, off);
        if (t == 0) out[0] = v;
    }
}

// ---------------------------------------------------------------------------
extern "C" void kernel_launch(void* const* d_in, const int* in_sizes, int n_in,
                              void* d_out, int out_size, void* d_ws, size_t ws_size,
                              hipStream_t stream) {
    const float* qr     = (const float*)d_in[0];   // (64,32,128) f32
    const float* doc    = (const float*)d_in[1];   // (64,16,256,128) f32
    const int*   dmask  = (const int*)d_in[2];     // (64,16,256) i32
    const float* labels = (const float*)d_in[3];   // (64,32) f32
    float* out = (float*)d_out;

    float* scores = (float*)d_ws;                  // 1024 f32

    scores_kernel<<<1024, 512, 0, stream>>>(qr, doc, dmask, scores);
    loss_kernel<<<1, 1024, 0, stream>>>(scores, labels, out);
}

// Round 13
// 30.015 us; speedup vs baseline: 1.4269x; 1.4269x over previous
//
#include <hip/hip_runtime.h>
#include <cmath>

#define EPSN 1e-12f

typedef _Float16 half8 __attribute__((ext_vector_type(8)));
typedef float f32x4 __attribute__((ext_vector_type(4)));

// ---------------------------------------------------------------------------
// scores_kernel: r10-EXACT (validated best, 30.05 us total). r4 hot-path
// structure + mask compaction (skip loading the ~50% masked tokens; their
// sim is exactly 0 in the reference). One block per (b, n, half), 256
// threads = 4 waves. Front-packed compact slot list; pad slots: no loads,
// zeroed B-image (chunk 0), invS=0 -> they inject 0 into the per-q max
// exactly when masked tokens exist (= reference semantics). f16 hi/lo
// 3-term MFMA; depth-2 register prefetch rotation; lgkmcnt-only barriers
// keep doc loads in flight across barriers.
// ---------------------------------------------------------------------------
__global__ __launch_bounds__(256, 4) void scores_kernel(
    const float* __restrict__ qr, const float* __restrict__ doc,
    const int* __restrict__ mask, float* __restrict__ pmax) {
    __shared__ __align__(16) char Aimg[16384];   // [qt2][kstep4][hl2][1024B]
    __shared__ __align__(16) char Bimg[16384];   // [tile8][hl2][kg4*16+col][16B]
    __shared__ float ssPart[256];
    __shared__ float invS[128];
    __shared__ int   compactS[128];
    __shared__ int   cntW[2];
    __shared__ float wq[4][32];

    int t = threadIdx.x, g = blockIdx.x;
    int bn = g >> 1, h = g & 1, b = g >> 5;
    int w = t >> 6, lane = t & 63, col = lane & 15;

    // ---- q loads first (arrive during compaction) ----
    int row = t >> 3, jb = t & 7;
    const float4* qsrc = (const float4*)(qr + ((size_t)b * 32 + row) * 128 + jb * 16);
    float4 v0 = qsrc[0], v1 = qsrc[1], v2 = qsrc[2], v3 = qsrc[3];

    // ---- mask load + ballot compaction (front-packed slot -> token) ----
    int myMask = 0;
    if (t < 128) myMask = mask[bn * 256 + h * 128 + t];
    unsigned long long bal = __ballot(myMask != 0);
    if (t < 128 && lane == 0) cntW[w] = __popcll(bal);
    __syncthreads();
    int cnt = cntW[0] + cntW[1];
    if (myMask) {
        int prefix = __popcll(bal & ((1ull << lane) - 1));
        int basec = (w == 1) ? cntW[0] : 0;
        compactS[basec + prefix] = t;
    }
    __syncthreads();

    int s = t & 127, kh = t >> 7;
    bool real = (s < cnt);
    int tokc = real ? compactS[s] : 0;

    // ---- doc prefetch: chunks 0 and 1 (guarded; exec-masked => no traffic
    //      for pad lanes; front-packing empties waves 1,3) ----
    const float4* dsrc = (const float4*)(doc + ((size_t)bn * 256 + h * 128 + tokc) * 128) + kh * 4;
    float4 rA0, rA1, rA2, rA3, rB0, rB1, rB2, rB3, rC0, rC1, rC2, rC3;
    if (real) {
        rA0 = dsrc[0];  rA1 = dsrc[1];  rA2 = dsrc[2],  rA3 = dsrc[3];
        rB0 = dsrc[8];  rB1 = dsrc[9];  rB2 = dsrc[10]; rB3 = dsrc[11];
    }

    // ---- q prologue: normalize + f16 hi/lo split + A-image (r4-exact) ----
    {
        float ss = v0.x*v0.x + v0.y*v0.y + v0.z*v0.z + v0.w*v0.w
                 + v1.x*v1.x + v1.y*v1.y + v1.z*v1.z + v1.w*v1.w
                 + v2.x*v2.x + v2.y*v2.y + v2.z*v2.z + v2.w*v2.w
                 + v3.x*v3.x + v3.y*v3.y + v3.z*v3.z + v3.w*v3.w;
        ss += __shfl_xor(ss, 1); ss += __shfl_xor(ss, 2); ss += __shfl_xor(ss, 4);
        float inv = 1.0f / fmaxf(sqrtf(ss), EPSN);
        int qt = row >> 4, kstep = jb >> 1;
        float4 vv[4] = { v0, v1, v2, v3 };
#pragma unroll
        for (int khh = 0; khh < 2; ++khh) {
            float xs[8] = { vv[2*khh].x,   vv[2*khh].y,   vv[2*khh].z,   vv[2*khh].w,
                            vv[2*khh+1].x, vv[2*khh+1].y, vv[2*khh+1].z, vv[2*khh+1].w };
            half8 hh, hl;
#pragma unroll
            for (int e = 0; e < 8; ++e) {
                float x = xs[e] * inv;
                _Float16 hv = (_Float16)x;
                hh[e] = hv;
                hl[e] = (_Float16)(x - (float)hv);
            }
            int quad = (jb & 1) * 2 + khh;
            int base = ((qt * 4 + kstep) * 2) * 1024 + ((row & 15) + quad * 16) * 16;
            *(half8*)(Aimg + base)        = hh;
            *(half8*)(Aimg + base + 1024) = hl;
        }
    }
    asm volatile("s_waitcnt lgkmcnt(0)" ::: "memory");
    __builtin_amdgcn_s_barrier();

    f32x4 acc[2][2];
    f32x4 zero = {0.f, 0.f, 0.f, 0.f};
    acc[0][0] = zero; acc[0][1] = zero; acc[1][0] = zero; acc[1][1] = zero;
    float ss_d = 0.f;

    int tile8 = s >> 4;
    int bo_base = tile8 * 2048 + (2 * kh) * 256 + (s & 15) * 16;

#define CHUNK(C, P0, P1, P2, P3, N0, N1, N2, N3, PREF, ISLAST) do {           \
    if ((PREF) && real) {                                                     \
        N0 = dsrc[(C + 2) * 8 + 0]; N1 = dsrc[(C + 2) * 8 + 1];               \
        N2 = dsrc[(C + 2) * 8 + 2]; N3 = dsrc[(C + 2) * 8 + 3];               \
    }                                                                         \
    if (real) {                                                               \
        ss_d += P0.x*P0.x + P0.y*P0.y + P0.z*P0.z + P0.w*P0.w;                \
        ss_d += P1.x*P1.x + P1.y*P1.y + P1.z*P1.z + P1.w*P1.w;                \
        ss_d += P2.x*P2.x + P2.y*P2.y + P2.z*P2.z + P2.w*P2.w;                \
        ss_d += P3.x*P3.x + P3.y*P3.y + P3.z*P3.z + P3.w*P3.w;                \
        float xa[8] = { P0.x, P0.y, P0.z, P0.w, P1.x, P1.y, P1.z, P1.w };     \
        float xb[8] = { P2.x, P2.y, P2.z, P2.w, P3.x, P3.y, P3.z, P3.w };     \
        half8 hha, hla, hhb, hlb;                                             \
        _Pragma("unroll")                                                     \
        for (int e = 0; e < 8; ++e) {                                         \
            float x = xa[e]; _Float16 hv = (_Float16)x;                       \
            hha[e] = hv; hla[e] = (_Float16)(x - (float)hv);                  \
            float y = xb[e]; _Float16 hw = (_Float16)y;                       \
            hhb[e] = hw; hlb[e] = (_Float16)(y - (float)hw);                  \
        }                                                                     \
        *(half8*)(Bimg + bo_base)              = hha;                         \
        *(half8*)(Bimg + bo_base + 1024)       = hla;                         \
        *(half8*)(Bimg + bo_base + 256)        = hhb;                         \
        *(half8*)(Bimg + bo_base + 256 + 1024) = hlb;                         \
    } else if ((C) == 0) {                                                    \
        half8 hz = {0,0,0,0,0,0,0,0};                                         \
        *(half8*)(Bimg + bo_base)              = hz;                          \
        *(half8*)(Bimg + bo_base + 1024)       = hz;                          \
        *(half8*)(Bimg + bo_base + 256)        = hz;                          \
        *(half8*)(Bimg + bo_base + 256 + 1024) = hz;                          \
    }                                                                         \
    if (ISLAST) ssPart[t] = ss_d;                                             \
    asm volatile("s_waitcnt lgkmcnt(0)" ::: "memory");                        \
    __builtin_amdgcn_s_barrier();                                             \
    if ((ISLAST) && t < 128) {                                                \
        float sst = ssPart[t] + ssPart[t + 128];                              \
        invS[t] = (t < cnt) ? (1.0f / fmaxf(sqrtf(sst), EPSN)) : 0.0f;        \
    }                                                                         \
    {                                                                         \
        int lo = lane << 4;                                                   \
        half8 a0h = *(const half8*)(Aimg + (((C) * 2 + 0) << 10) + lo);       \
        half8 a0l = *(const half8*)(Aimg + (((C) * 2 + 1) << 10) + lo);       \
        half8 a1h = *(const half8*)(Aimg + (((4 + (C)) * 2 + 0) << 10) + lo); \
        half8 a1l = *(const half8*)(Aimg + (((4 + (C)) * 2 + 1) << 10) + lo); \
        _Pragma("unroll")                                                     \
        for (int nt = 0; nt < 2; ++nt) {                                      \
            int tile = w * 2 + nt;                                            \
            half8 bh = *(const half8*)(Bimg + tile * 2048 + lo);              \
            half8 bl = *(const half8*)(Bimg + tile * 2048 + 1024 + lo);       \
            acc[0][nt] = __builtin_amdgcn_mfma_f32_16x16x32_f16(a0l, bh, acc[0][nt], 0, 0, 0); \
            acc[0][nt] = __builtin_amdgcn_mfma_f32_16x16x32_f16(a0h, bl, acc[0][nt], 0, 0, 0); \
            acc[0][nt] = __builtin_amdgcn_mfma_f32_16x16x32_f16(a0h, bh, acc[0][nt], 0, 0, 0); \
            acc[1][nt] = __builtin_amdgcn_mfma_f32_16x16x32_f16(a1l, bh, acc[1][nt], 0, 0, 0); \
            acc[1][nt] = __builtin_amdgcn_mfma_f32_16x16x32_f16(a1h, bl, acc[1][nt], 0, 0, 0); \
            acc[1][nt] = __builtin_amdgcn_mfma_f32_16x16x32_f16(a1h, bh, acc[1][nt], 0, 0, 0); \
        }                                                                     \
    }                                                                         \
    asm volatile("s_waitcnt lgkmcnt(0)" ::: "memory");                        \
    __builtin_amdgcn_s_barrier();                                             \
} while (0)

    // rotation: c0=A c1=B c2=C c3=A; prefetch c+2 during chunk c
    CHUNK(0, rA0, rA1, rA2, rA3, rC0, rC1, rC2, rC3, 1, false);
    CHUNK(1, rB0, rB1, rB2, rB3, rA0, rA1, rA2, rA3, 1, false);
    CHUNK(2, rC0, rC1, rC2, rC3, rB0, rB1, rB2, rB3, 0, false);
    CHUNK(3, rA0, rA1, rA2, rA3, rB0, rB1, rB2, rB3, 0, true);
#undef CHUNK

    // ---- epilogue: inv-norm, max over this block's slots (r4-exact) ----
    float inv0 = invS[w * 32 + col];
    float inv1 = invS[w * 32 + 16 + col];
    float m8[8];
#pragma unroll
    for (int qt = 0; qt < 2; ++qt)
#pragma unroll
        for (int rr = 0; rr < 4; ++rr)
            m8[qt * 4 + rr] = fmaxf(acc[qt][0][rr] * inv0, acc[qt][1][rr] * inv1);
#pragma unroll
    for (int off = 1; off < 16; off <<= 1)
#pragma unroll
        for (int i = 0; i < 8; ++i) m8[i] = fmaxf(m8[i], __shfl_xor(m8[i], off));
    if (col == 0) {
        int rg = lane >> 4;   // C/D: row = (lane>>4)*4 + reg (m89-verified)
#pragma unroll
        for (int qt = 0; qt < 2; ++qt)
#pragma unroll
            for (int rr = 0; rr < 4; ++rr) wq[w][qt * 16 + rg * 4 + rr] = m8[qt * 4 + rr];
    }
    __syncthreads();
    if (w == 0 && lane < 32) {
        float v = fmaxf(fmaxf(wq[0][lane], wq[1][lane]), fmaxf(wq[2][lane], wq[3][lane]));
        pmax[(size_t)g * 32 + lane] = v;
    }
}

// ---------------------------------------------------------------------------
// lossb_kernel: one block per b (r3/r8-validated). Parallel 4 KB pmax gather,
// combine half-block maxes into scores, 256 pair losses -> partial[b].
// ---------------------------------------------------------------------------
__global__ __launch_bounds__(256) void lossb_kernel(const float* __restrict__ pmax,
                                                    const float* __restrict__ labels,
                                                    float* __restrict__ partial) {
    __shared__ float pmL[1024];
    __shared__ float sc[16], ysS[16], idxS[16];
    __shared__ float wsum[4];
    int b = blockIdx.x, t = threadIdx.x;
    ((float4*)pmL)[t] = ((const float4*)(pmax + (size_t)b * 1024))[t];
    if (t < 16) { ysS[t] = labels[b * 32 + t]; idxS[t] = labels[b * 32 + 16 + t]; }
    __syncthreads();
    {
        int n = t >> 4, qq = t & 15;
        float v = fmaxf(pmL[n * 64 + qq],      pmL[n * 64 + 32 + qq])
                + fmaxf(pmL[n * 64 + 16 + qq], pmL[n * 64 + 48 + qq]);
        v += __shfl_xor(v, 1); v += __shfl_xor(v, 2);
        v += __shfl_xor(v, 4); v += __shfl_xor(v, 8);
        if (qq == 0) sc[n] = v;
    }
    __syncthreads();
    int i = t >> 4, j = t & 15;
    float v = 0.f;
    if (ysS[i] - ysS[j] > 0.f) {
        float wgt = fabsf(idxS[i] - idxS[j]);
        float d = (i <= j) ? (sc[i] - sc[j]) : 0.f;
        v = log1pf(expf(-d)) * wgt;
    }
#pragma unroll
    for (int off = 1; off < 64; off <<= 1) v += __shfl_xor(v, off);
    int lane = t & 63;
    if (lane == 0) wsum[t >> 6] = v;
    __syncthreads();
    if (t == 0) partial[b] = wsum[0] + wsum[1] + wsum[2] + wsum[3];
}

__global__ void lossfin_kernel(const float* __restrict__ partial, float* __restrict__ out) {
    int t = threadIdx.x;   // 64 threads, one wave
    float v = partial[t];
#pragma unroll
    for (int off = 1; off < 64; off <<= 1) v += __shfl_xor(v, off);
    if (t == 0) out[0] = v;
}

// ---------------------------------------------------------------------------
extern "C" void kernel_launch(void* const* d_in, const int* in_sizes, int n_in,
                              void* d_out, int out_size, void* d_ws, size_t ws_size,
                              hipStream_t stream) {
    const float* qr     = (const float*)d_in[0];   // (64,32,128) f32
    const float* doc    = (const float*)d_in[1];   // (64,16,256,128) f32
    const int*   dmask  = (const int*)d_in[2];     // (64,16,256) i32
    const float* labels = (const float*)d_in[3];   // (64,32) f32
    float* out = (float*)d_out;

    float* pmax    = (float*)d_ws;                 // 2048*32 f32 = 256 KB
    float* partial = pmax + 2048 * 32;             // 64 f32

    scores_kernel<<<2048, 256, 0, stream>>>(qr, doc, dmask, pmax);
    lossb_kernel<<<64, 256, 0, stream>>>(pmax, labels, partial);
    lossfin_kernel<<<1, 64, 0, stream>>>(partial, out);
}